// Round 1
// baseline (434.359 us; speedup 1.0000x reference)
//
#include <hip/hip_runtime.h>

#define H_   128
#define W_   128
#define CIN  64
#define COUT 64
#define B_   8
#define HW_  (H_*W_)

// ---------------------------------------------------------------------------
// Kernel 1: offsets conv  o[b][j][h][w] = bias[j] + sum_{c,ki,kj} w[j][c][ki][kj]*x_pad
// Block: 256 threads = 2 rows of 128. Grid: B * H/2 = 512.
// x rows staged in LDS per 16-channel chunk.
// ---------------------------------------------------------------------------
__global__ __launch_bounds__(256) void offsets_kernel(
    const float* __restrict__ x, const float* __restrict__ ow,
    const float* __restrict__ ob, float* __restrict__ o)
{
    __shared__ float xs[16][4][W_];                 // 32 KB
    __shared__ __align__(16) float wl[576][4];      // [c*9+kk][j], 9.2 KB

    int tid = threadIdx.x;
    int blk = blockIdx.x;
    int b  = blk >> 6;
    int h0 = (blk & 63) << 1;

    for (int idx = tid; idx < 2304; idx += 256) {
        int ck = idx >> 2, j = idx & 3;
        int c = ck / 9, kk = ck - c * 9;
        wl[ck][j] = ow[(j * CIN + c) * 9 + kk];
    }

    float acc0 = 0.f, acc1 = 0.f, acc2 = 0.f, acc3 = 0.f;
    int hr = tid >> 7;          // row within block (0/1)
    int w  = tid & 127;

    for (int cc = 0; cc < 4; ++cc) {
        __syncthreads();
        for (int idx = tid; idx < 16 * 4 * W_; idx += 256) {
            int c_l = idx >> 9;
            int rem = idx & 511;
            int row = rem >> 7;
            int ww  = rem & 127;
            int gy  = h0 - 1 + row;
            float v = 0.f;
            if (gy >= 0 && gy < H_)
                v = x[((size_t)(b * CIN + cc * 16 + c_l) * H_ + gy) * W_ + ww];
            xs[c_l][row][ww] = v;
        }
        __syncthreads();
        for (int c_l = 0; c_l < 16; ++c_l) {
            int ckbase = (cc * 16 + c_l) * 9;
            #pragma unroll
            for (int ki = 0; ki < 3; ++ki) {
                #pragma unroll
                for (int kj = 0; kj < 3; ++kj) {
                    int wx = w - 1 + kj;
                    float v = (wx >= 0 && wx < W_) ? xs[c_l][hr + ki][wx] : 0.f;
                    float4 wv = *(const float4*)&wl[ckbase + ki * 3 + kj][0];
                    acc0 += v * wv.x; acc1 += v * wv.y;
                    acc2 += v * wv.z; acc3 += v * wv.w;
                }
            }
        }
    }

    int h = h0 + hr;
    size_t base = ((size_t)(b * 4) * H_ + h) * W_ + w;
    o[base]            = acc0 + ob[0];
    o[base + HW_]      = acc1 + ob[1];
    o[base + 2 * HW_]  = acc2 + ob[2];
    o[base + 3 * HW_]  = acc3 + ob[3];
}

// ---------------------------------------------------------------------------
// Kernel 1b: transpose weight (COUT,CIN,3,3) -> wT[ck][co], ck = c*9+k
// ---------------------------------------------------------------------------
__global__ void wtrans_kernel(const float* __restrict__ w, float* __restrict__ wT)
{
    int idx = blockIdx.x * 256 + threadIdx.x;
    if (idx < 576 * COUT) {
        int ck = idx >> 6, co = idx & 63;
        wT[idx] = w[co * 576 + ck];
    }
}

// ---------------------------------------------------------------------------
// Kernel 2: fused bilinear gather + einsum.
// Block: 256 threads, tile = 64 pixels (one b,h, half row) x 64 c_out.
// Phase A: per (pixel,k) precompute 4 clipped addrs + 4 validity-folded weights.
// Phase B (8 chunks of 8 channels): gather samples into LDS [72][64],
//   stage weight chunk [72][64], then 16x16-thread register-tiled matmul,
//   acc[4][4] per thread.
// ---------------------------------------------------------------------------
__global__ __launch_bounds__(256) void main_kernel(
    const float* __restrict__ x, const float* __restrict__ o,
    const float* __restrict__ wT, float* __restrict__ out)
{
    __shared__ __align__(16) int   aaddr[9][64][4];   // 9.2 KB
    __shared__ __align__(16) float awt[9][64][4];     // 9.2 KB
    __shared__ __align__(16) float s_lds[72 * 64];    // 18.4 KB
    __shared__ __align__(16) float w_lds[72 * 64];    // 18.4 KB

    int tid = threadIdx.x;
    int blk = blockIdx.x;
    int b   = blk >> 8;
    int rem = blk & 255;
    int h   = rem >> 1;
    int w0  = (rem & 1) << 6;

    // ---- Phase A: sampling geometry (shared across all 64 channels) ----
    for (int idx = tid; idx < 576; idx += 256) {
        int p = idx & 63;
        int k = idx >> 6;
        int w = w0 + p;
        size_t obase = ((size_t)(b * 4) * H_ + h) * W_ + w;
        float t  = o[obase];
        float bo = o[obase + HW_];
        float l  = o[obase + 2 * HW_];
        float r  = o[obase + 3 * HW_];
        float dy, dx;
        switch (k) {
            case 0: dy = t;   dx = 0.f; break;
            case 1: dy = bo;  dx = t;   break;
            case 2: dy = 0.f; dx = bo;  break;
            case 3: dy = t;   dx = 0.f; break;
            case 4: dy = bo;  dx = l;   break;
            case 5: dy = l;   dx = l;   break;
            case 6: dy = 0.f; dx = 0.f; break;
            case 7: dy = 0.f; dx = r;   break;
            default: dy = r;  dx = r;   break;
        }
        float py = (float)(h - 1 + k / 3) + dy;
        float px = (float)(w - 1 + (k % 3)) + dx;
        float y0f = floorf(py), x0f = floorf(px);
        float ly = py - y0f, lx = px - x0f;
        int y0 = (int)y0f, x0 = (int)x0f;
        int y1 = y0 + 1,   x1 = x0 + 1;
        bool vy0 = ((unsigned)y0 < (unsigned)H_);
        bool vy1 = ((unsigned)y1 < (unsigned)H_);
        bool vx0 = ((unsigned)x0 < (unsigned)W_);
        bool vx1 = ((unsigned)x1 < (unsigned)W_);
        int y0c = min(max(y0, 0), H_ - 1), y1c = min(max(y1, 0), H_ - 1);
        int x0c = min(max(x0, 0), W_ - 1), x1c = min(max(x1, 0), W_ - 1);
        aaddr[k][p][0] = y0c * W_ + x0c;
        aaddr[k][p][1] = y0c * W_ + x1c;
        aaddr[k][p][2] = y1c * W_ + x0c;
        aaddr[k][p][3] = y1c * W_ + x1c;
        float omly = 1.f - ly, omlx = 1.f - lx;
        awt[k][p][0] = (vy0 && vx0) ? omly * omlx : 0.f;
        awt[k][p][1] = (vy0 && vx1) ? omly * lx   : 0.f;
        awt[k][p][2] = (vy1 && vx0) ? ly * omlx   : 0.f;
        awt[k][p][3] = (vy1 && vx1) ? ly * lx     : 0.f;
    }
    __syncthreads();

    float acc[4][4] = {};
    int tp = tid & 15;     // pixel group  (4 pixels)
    int tc = tid >> 4;     // c_out group  (4 outputs)
    const float4* wT4 = (const float4*)wT;

    for (int cc = 0; cc < 8; ++cc) {
        // ---- B1: gather 8 channels x 9 taps x 64 pixels into LDS ----
        for (int idx = tid; idx < 72 * 64; idx += 256) {
            int p = idx & 63;
            int r = idx >> 6;           // 0..71  = c_l*9 + k
            int k   = r % 9;
            int c_l = r / 9;
            int4   a4 = *(const int4*)&aaddr[k][p][0];
            float4 w4 = *(const float4*)&awt[k][p][0];
            const float* xb = x + ((size_t)(b * CIN + cc * 8 + c_l) << 14);
            float s = w4.x * xb[a4.x] + w4.y * xb[a4.y]
                    + w4.z * xb[a4.z] + w4.w * xb[a4.w];
            s_lds[idx] = s;
        }
        // ---- stage weight chunk (contiguous rows of wT) ----
        for (int idx = tid; idx < 1152; idx += 256) {
            ((float4*)w_lds)[idx] = wT4[cc * 1152 + idx];
        }
        __syncthreads();
        // ---- B2: register-tiled matmul over 72 k-rows ----
        #pragma unroll 8
        for (int r = 0; r < 72; ++r) {
            float4 sv = *(const float4*)&s_lds[r * 64 + tp * 4];
            float4 wv = *(const float4*)&w_lds[r * 64 + tc * 4];
            float svv[4] = {sv.x, sv.y, sv.z, sv.w};
            float wvv[4] = {wv.x, wv.y, wv.z, wv.w};
            #pragma unroll
            for (int i = 0; i < 4; ++i)
                #pragma unroll
                for (int j = 0; j < 4; ++j)
                    acc[i][j] += svv[i] * wvv[j];
        }
        __syncthreads();
    }

    // ---- epilogue: float4 stores along w ----
    #pragma unroll
    for (int j = 0; j < 4; ++j) {
        int co = tc * 4 + j;
        size_t ob2 = ((size_t)(b * COUT + co) * H_ + h) * W_ + w0 + tp * 4;
        float4 v = make_float4(acc[0][j], acc[1][j], acc[2][j], acc[3][j]);
        *(float4*)&out[ob2] = v;
    }
}

extern "C" void kernel_launch(void* const* d_in, const int* in_sizes, int n_in,
                              void* d_out, int out_size, void* d_ws, size_t ws_size,
                              hipStream_t stream)
{
    const float* x  = (const float*)d_in[0];
    const float* ow = (const float*)d_in[1];
    const float* ob = (const float*)d_in[2];
    const float* wt = (const float*)d_in[3];
    float* out  = (float*)d_out;
    float* o_ws = (float*)d_ws;                 // (B,4,H,W) = 524288 floats
    float* wT   = o_ws + (size_t)B_ * 4 * HW_;  // (576,64)  = 36864 floats

    offsets_kernel<<<dim3(512), dim3(256), 0, stream>>>(x, ow, ob, o_ws);
    wtrans_kernel<<<dim3(144), dim3(256), 0, stream>>>(wt, wT);
    main_kernel<<<dim3(2048), dim3(256), 0, stream>>>(x, o_ws, wT, out);
}

// Round 2
// 408.331 us; speedup vs baseline: 1.0637x; 1.0637x over previous
//
#include <hip/hip_runtime.h>

#define H_   128
#define W_   128
#define CIN  64
#define COUT 64
#define B_   8
#define HW_  (H_*W_)

typedef __attribute__((ext_vector_type(8))) short  short8;
typedef __attribute__((ext_vector_type(8))) __bf16 bf16x8;
typedef __attribute__((ext_vector_type(4))) float  f32x4;

__device__ __forceinline__ ushort bf16r(float f) {
    uint u = __builtin_bit_cast(uint, f);
    u += 0x7fff + ((u >> 16) & 1);          // RNE
    return (ushort)(u >> 16);
}

// ---------------------------------------------------------------------------
// prep: owT[ck][j] = ow[j][ck]  (fp32, for uniform scalar loads)
//       wTT2[kk][co][c] = bf16(weight[co][c][kk])   (B^T per K-chunk)
// ---------------------------------------------------------------------------
__global__ void prep_kernel(const float* __restrict__ wt, const float* __restrict__ ow,
                            float* __restrict__ owT, ushort* __restrict__ wTT2)
{
    int idx = blockIdx.x * 256 + threadIdx.x;
    if (idx < 9 * 64 * 64) {
        int kk = idx >> 12;
        int r  = idx & 4095;
        int co = r >> 6, c = r & 63;
        wTT2[idx] = bf16r(wt[(co * 64 + c) * 9 + kk]);
    }
    if (idx < 576 * 4) {
        int ck = idx >> 2, j = idx & 3;
        owT[idx] = ow[j * 576 + ck];
    }
}

// ---------------------------------------------------------------------------
// offsets conv: one block per (b,h) row, 128 threads (= w).
// Weights via wave-uniform global float4 (scalar-loaded); padded LDS rows.
// ---------------------------------------------------------------------------
__global__ __launch_bounds__(128) void offsets_kernel(
    const float* __restrict__ x, const float* __restrict__ owT,
    const float* __restrict__ ob, float* __restrict__ o)
{
    __shared__ float xs[16][3][132];        // 25.3 KB, w-padded by 2 both sides

    int tid = threadIdx.x;
    int blk = blockIdx.x;
    int b = blk >> 7, h = blk & 127;
    int w = tid;

    for (int i = tid; i < 16 * 3; i += 128) {
        int c = i / 3, r = i - c * 3;
        xs[c][r][0] = 0.f; xs[c][r][1] = 0.f;
        xs[c][r][130] = 0.f; xs[c][r][131] = 0.f;
    }

    float a0 = 0.f, a1 = 0.f, a2 = 0.f, a3 = 0.f;
    const float4* owT4 = (const float4*)owT;

    for (int cc = 0; cc < 4; ++cc) {
        __syncthreads();
        for (int idx = tid; idx < 16 * 3 * 128; idx += 128) {
            int c_l = idx / 384;
            int rem = idx - c_l * 384;
            int row = rem >> 7, ww = rem & 127;
            int gy = h - 1 + row;
            float v = 0.f;
            if ((unsigned)gy < (unsigned)H_)
                v = x[((size_t)(b * CIN + cc * 16 + c_l) * H_ + gy) * W_ + ww];
            xs[c_l][row][ww + 2] = v;
        }
        __syncthreads();
        #pragma unroll
        for (int c_l = 0; c_l < 16; ++c_l) {
            int ckb = (cc * 16 + c_l) * 9;
            #pragma unroll
            for (int ki = 0; ki < 3; ++ki) {
                #pragma unroll
                for (int kj = 0; kj < 3; ++kj) {
                    float v = xs[c_l][ki][w + kj + 1];   // (w-1+kj)+2
                    float4 wv = owT4[ckb + ki * 3 + kj]; // uniform -> s_load
                    a0 += v * wv.x; a1 += v * wv.y;
                    a2 += v * wv.z; a3 += v * wv.w;
                }
            }
        }
    }

    size_t base = ((size_t)(b * 4) * H_ + h) * W_ + w;
    o[base]           = a0 + ob[0];
    o[base + HW_]     = a1 + ob[1];
    o[base + 2 * HW_] = a2 + ob[2];
    o[base + 3 * HW_] = a3 + ob[3];
}

// ---------------------------------------------------------------------------
// main: one block per (b,h) row: 128 px x 64 cout, K = 576 ordered kk*64+c.
// 128 threads = 2 waves; each wave -> 64px x 64co tile via 16x16x32 bf16 MFMA.
// Per chunk (fixed kk): geometry in regs, gather 64 channels -> a_lds bf16.
// ---------------------------------------------------------------------------
__global__ __launch_bounds__(128) void main_kernel(
    const float* __restrict__ x, const float* __restrict__ o,
    const ushort* __restrict__ wTT2, float* __restrict__ out)
{
    __shared__ ushort a_lds[128][72];       // [px][K-chunk], 18.4 KB
    __shared__ ushort w_lds[64][72];        // [co][K-chunk],  9.2 KB

    int tid  = threadIdx.x;
    int blk  = blockIdx.x;
    int b    = blk >> 7, h = blk & 127;
    int w    = tid;
    int lane = tid & 63, wid = tid >> 6;

    size_t obase = ((size_t)(b * 4) * H_ + h) * W_ + w;
    float t  = o[obase];
    float bo = o[obase + HW_];
    float l_ = o[obase + 2 * HW_];
    float r_ = o[obase + 3 * HW_];

    const float* xb = x + ((size_t)b * CIN * HW_);

    f32x4 zero4 = {0.f, 0.f, 0.f, 0.f};
    f32x4 acc[4][4];
    #pragma unroll
    for (int i = 0; i < 4; ++i)
        #pragma unroll
        for (int j = 0; j < 4; ++j) acc[i][j] = zero4;

    for (int cc = 0; cc < 9; ++cc) {
        // ---- geometry (registers only; kk = cc fixed for this chunk) ----
        float dy, dx;
        switch (cc) {
            case 0: dy = t;   dx = 0.f; break;
            case 1: dy = bo;  dx = t;   break;
            case 2: dy = 0.f; dx = bo;  break;
            case 3: dy = t;   dx = 0.f; break;
            case 4: dy = bo;  dx = l_;  break;
            case 5: dy = l_;  dx = l_;  break;
            case 6: dy = 0.f; dx = 0.f; break;
            case 7: dy = 0.f; dx = r_;  break;
            default: dy = r_; dx = r_;  break;
        }
        int ki = cc / 3, kj = cc - ki * 3;
        float py  = (float)(h - 1 + ki) + dy;
        float pxf = (float)(w - 1 + kj) + dx;
        float y0f = floorf(py), x0f = floorf(pxf);
        float ly = py - y0f, lx = pxf - x0f;
        int y0 = (int)y0f, x0 = (int)x0f;
        int y1 = y0 + 1,   x1 = x0 + 1;
        bool vy0 = ((unsigned)y0 < (unsigned)H_);
        bool vy1 = ((unsigned)y1 < (unsigned)H_);
        bool vx0 = ((unsigned)x0 < (unsigned)W_);
        bool vx1 = ((unsigned)x1 < (unsigned)W_);
        int y0c = min(max(y0, 0), H_ - 1), y1c = min(max(y1, 0), H_ - 1);
        int x0c = min(max(x0, 0), W_ - 1), x1c = min(max(x1, 0), W_ - 1);
        int ia0 = y0c * W_ + x0c, ia1 = y0c * W_ + x1c;
        int ia2 = y1c * W_ + x0c, ia3 = y1c * W_ + x1c;
        float omly = 1.f - ly, omlx = 1.f - lx;
        float wt0 = (vy0 && vx0) ? omly * omlx : 0.f;
        float wt1 = (vy0 && vx1) ? omly * lx   : 0.f;
        float wt2 = (vy1 && vx0) ? ly * omlx   : 0.f;
        float wt3 = (vy1 && vx1) ? ly * lx     : 0.f;

        // ---- gather 64 channels for (px=tid, kk=cc) ----
        #pragma unroll
        for (int c8 = 0; c8 < 8; ++c8) {
            uint pk[4];
            #pragma unroll
            for (int i2 = 0; i2 < 4; ++i2) {
                const float* xc0 = xb + ((size_t)(c8 * 8 + i2 * 2) << 14);
                const float* xc1 = xb + ((size_t)(c8 * 8 + i2 * 2 + 1) << 14);
                float s0 = wt0 * xc0[ia0] + wt1 * xc0[ia1]
                         + wt2 * xc0[ia2] + wt3 * xc0[ia3];
                float s1 = wt0 * xc1[ia0] + wt1 * xc1[ia1]
                         + wt2 * xc1[ia2] + wt3 * xc1[ia3];
                pk[i2] = (uint)bf16r(s0) | ((uint)bf16r(s1) << 16);
            }
            *(uint4*)&a_lds[tid][c8 * 8] = make_uint4(pk[0], pk[1], pk[2], pk[3]);
        }

        // ---- stage B chunk: w_lds[co][c] from wTT2[cc][co][c] ----
        {
            const uint4* src = (const uint4*)(wTT2 + cc * 4096);
            #pragma unroll
            for (int q = 0; q < 4; ++q) {
                int idx = tid + q * 128;            // 0..511
                int co = idx >> 3, c0 = (idx & 7) * 8;
                *(uint4*)&w_lds[co][c0] = src[idx];
            }
        }
        __syncthreads();

        // ---- MFMA: 2 k-slices x (4 m-tiles x 4 n-tiles) ----
        #pragma unroll
        for (int s = 0; s < 2; ++s) {
            int krow = s * 32 + (lane >> 4) * 8;
            bf16x8 af[4];
            #pragma unroll
            for (int i = 0; i < 4; ++i)
                af[i] = __builtin_bit_cast(bf16x8,
                    *(const short8*)&a_lds[wid * 64 + i * 16 + (lane & 15)][krow]);
            #pragma unroll
            for (int j = 0; j < 4; ++j) {
                bf16x8 bf = __builtin_bit_cast(bf16x8,
                    *(const short8*)&w_lds[j * 16 + (lane & 15)][krow]);
                #pragma unroll
                for (int i = 0; i < 4; ++i)
                    acc[i][j] = __builtin_amdgcn_mfma_f32_16x16x32_bf16(
                        af[i], bf, acc[i][j], 0, 0, 0);
            }
        }
        __syncthreads();
    }

    // ---- epilogue: D row = (lane>>4)*4+reg (px/w), col = lane&15 (co) ----
    #pragma unroll
    for (int i = 0; i < 4; ++i) {
        int pr = wid * 64 + i * 16 + (lane >> 4) * 4;
        #pragma unroll
        for (int j = 0; j < 4; ++j) {
            int co = j * 16 + (lane & 15);
            *(float4*)&out[((size_t)(b * COUT + co) * H_ + h) * W_ + pr] =
                *(float4*)&acc[i][j];
        }
    }
}

extern "C" void kernel_launch(void* const* d_in, const int* in_sizes, int n_in,
                              void* d_out, int out_size, void* d_ws, size_t ws_size,
                              hipStream_t stream)
{
    const float* x  = (const float*)d_in[0];
    const float* ow = (const float*)d_in[1];
    const float* ob = (const float*)d_in[2];
    const float* wt = (const float*)d_in[3];
    float* out = (float*)d_out;

    float*  o_ws = (float*)d_ws;                          // 524288 f
    float*  owT  = o_ws + (size_t)B_ * 4 * HW_;           // 2304 f
    ushort* wTT2 = (ushort*)(owT + 2304);                 // 36864 bf16

    prep_kernel<<<dim3(144), dim3(256), 0, stream>>>(wt, ow, owT, wTT2);
    offsets_kernel<<<dim3(1024), dim3(128), 0, stream>>>(x, owT, ob, o_ws);
    main_kernel<<<dim3(1024), dim3(128), 0, stream>>>(x, o_ws, wTT2, out);
}